// Round 1
// baseline (19190.335 us; speedup 1.0000x reference)
//
#include <hip/hip_runtime.h>
#include <hip/hip_bf16.h>

#define B_TOT 2048
#define NTS   200
#define DIN   128
#define LATN  256
#define NUN   512
#define CATN  640
#define ROWS  16
#define NBLK  (B_TOT/ROWS)   // 128
#define NTHR  512

#define CATP  (CATN+8)       // 648  (row stride, bf16; 1296B -> bank step 4)
#define HURP  (2*NUN+8)      // 1032 (2064B -> bank step 4)

// ws offsets in bf16 elements (all [N][K] transposed)
#define OFF_WO1   0          // [256][256]
#define OFF_WO2   65536      // [256][256]
#define OFF_WUR1  131072     // [1024][640]  rows 0-511 Wu1-cols, 512-1023 Wr1-cols
#define OFF_WUR2  786432     // [512][512]   rows 0-255 Wu2-cols, 256-511 Wr2-cols
#define OFF_WN1   1048576    // [512][640]
#define OFF_WN2   1376256    // [512][512]
#define WS_ELEMS  1638400

typedef __attribute__((ext_vector_type(8))) short s8v;
typedef __attribute__((ext_vector_type(4))) float f4v;

__device__ __forceinline__ unsigned short f2bf(float x) {
    __hip_bfloat16 h = __float2bfloat16(x);
    unsigned short u;
    __builtin_memcpy(&u, &h, 2);
    return u;
}

// out[16, c0 + NFR*16) += A[16,K] @ WT^T ; A is LDS bf16 (stride strideA elems),
// WT is [N][K] bf16 in global. MFMA 16x16x32 layout:
//  A: lane l holds A[l&15][k0 + 8*(l>>4) .. +8]
//  B: lane l holds W [k0 + 8*(l>>4) .. +8][c0+f*16+(l&15)]  == WT[(c0+f*16+(l&15))][k..]
//  D: lane l reg i -> row (l>>4)*4+i, col c0+f*16+(l&15)
template<int K, int NFR>
__device__ __forceinline__ void mmloop(const unsigned short* A, int strideA,
                                       const unsigned short* Wp, int Kw, int c0,
                                       f4v* acc, int arow, int ah)
{
    const unsigned short* ap  = A + arow * strideA + ah * 8;
    const unsigned short* bp0 = Wp + (c0 + arow) * Kw + ah * 8;
#pragma unroll 2
    for (int k0 = 0; k0 < K; k0 += 32) {
        s8v av = *(const s8v*)(ap + k0);
#pragma unroll
        for (int f = 0; f < NFR; ++f) {
            s8v bv = *(const s8v*)(bp0 + f * 16 * Kw + k0);
            acc[f] = __builtin_amdgcn_mfma_f32_16x16x32_bf16(av, bv, acc[f], 0, 0, 0);
        }
    }
}

// ---------------- weight prep: fp32 [K][N] -> bf16 [N][K] ----------------
__global__ void prep_weights(const float* __restrict__ Wu1, const float* __restrict__ Wr1,
                             const float* __restrict__ Wu2, const float* __restrict__ Wr2,
                             const float* __restrict__ Wn1, const float* __restrict__ Wn2,
                             const float* __restrict__ Wo1, const float* __restrict__ Wo2,
                             unsigned short* __restrict__ ws)
{
    int idx = blockIdx.x * 256 + threadIdx.x;
    if (idx >= WS_ELEMS) return;
    float v;
    if (idx < OFF_WO2) {                       // WoT1
        int l = idx - OFF_WO1, j = l >> 8, k = l & 255;
        v = Wo1[k * 256 + j];
    } else if (idx < OFF_WUR1) {               // WoT2
        int l = idx - OFF_WO2, j = l >> 8, k = l & 255;
        v = Wo2[k * 256 + j];
    } else if (idx < OFF_WUR2) {               // WurT1 [1024][640]
        int l = idx - OFF_WUR1, j = l / 640, k = l - j * 640;
        v = (j < 512) ? Wu1[k * 512 + j] : Wr1[k * 512 + (j - 512)];
    } else if (idx < OFF_WN1) {                // WurT2 [512][512]
        int l = idx - OFF_WUR2, j = l >> 9, k = l & 511;
        v = (j < 256) ? Wu2[k * 256 + j] : Wr2[k * 256 + (j - 256)];
    } else if (idx < OFF_WN2) {                // WnT1 [512][640]
        int l = idx - OFF_WN1, j = l / 640, k = l - j * 640;
        v = Wn1[k * 512 + j];
    } else {                                   // WnT2 [512][512]
        int l = idx - OFF_WN2, j = l >> 9, k = l & 511;
        v = Wn2[k * 512 + j];
    }
    ws[idx] = f2bf(v);
}

// ---------------- main persistent kernel ----------------
__launch_bounds__(NTHR, 1)
__global__ void odernn_main(const float* __restrict__ data, const float* __restrict__ tsg,
                            const float* __restrict__ bu1, const float* __restrict__ bu2,
                            const float* __restrict__ br1, const float* __restrict__ br2,
                            const float* __restrict__ bn1, const float* __restrict__ bn2,
                            const float* __restrict__ bo1, const float* __restrict__ bo2,
                            const float* __restrict__ Wt1, const float* __restrict__ bt1,
                            const float* __restrict__ Wt2, const float* __restrict__ bt2,
                            const unsigned short* __restrict__ W,
                            float* __restrict__ out)
{
    __shared__ unsigned short cat[ROWS][CATP];   // y_ode(bf16)|s(bf16)|x(bf16); later r-scaled
    __shared__ unsigned short hur[ROWS][HURP];   // h_o / hu|hr / hn  (bf16, overlaid in time)
    __shared__ float yf [ROWS][LATN];
    __shared__ float sf [ROWS][LATN];
    __shared__ float yof[ROWS][LATN];
    __shared__ float uf [ROWS][LATN];
    __shared__ float rf [ROWS][LATN];
    __shared__ float z1s[ROWS][100];
    __shared__ float msum[ROWS];

    const int tid  = threadIdx.x;
    const int lane = tid & 63;
    const int w    = tid >> 6;       // wave 0..7
    const int arow = lane & 15;
    const int ah   = lane >> 4;
    const int r0   = blockIdx.x * ROWS;

    // init state
    for (int i = tid; i < ROWS * LATN; i += NTHR) {
        yf[i >> 8][i & 255] = 0.f;
        sf[i >> 8][i & 255] = 0.f;
    }
    for (int i = tid; i < ROWS * 512; i += NTHR)
        cat[i >> 9][i & 511] = 0;    // bf16 zero for y|s slots
    __syncthreads();

    const int xr = tid >> 5;          // x-load: row 0..15
    const int xc = (tid & 31) * 4;    // col 0..124

    for (int t = 0; t < NTS; ++t) {
        const int tstep = 199 - t;
        const float dtv = (t == 0) ? -0.01f : (tsg[199 - t] - tsg[200 - t]);

        // ---- load x_t -> cat[.,512:640], start mask sums ----
        if (tid < ROWS) msum[tid] = 0.f;
        const float4 xv = *(const float4*)(data + ((size_t)(r0 + xr) * NTS + tstep) * DIN + xc);
        cat[xr][512 + xc + 0] = f2bf(xv.x);
        cat[xr][512 + xc + 1] = f2bf(xv.y);
        cat[xr][512 + xc + 2] = f2bf(xv.z);
        cat[xr][512 + xc + 3] = f2bf(xv.w);
        const float mpart = (xc >= 64) ? (xv.x + xv.y + xv.z + xv.w) : 0.f;
        __syncthreads();
        if (xc >= 64) atomicAdd(&msum[xr], mpart);

        // ---- G_o1: h_o = tanh(y @ Wo1 + bo1) -> hur[:,0:256] ----
        {
            f4v a[2];
#pragma unroll
            for (int f = 0; f < 2; ++f) {
                float b = bo1[w * 32 + f * 16 + arow];
                a[f] = (f4v){b, b, b, b};
            }
            mmloop<256, 2>(&cat[0][0], CATP, W + OFF_WO1, 256, w * 32, a, arow, ah);
#pragma unroll
            for (int f = 0; f < 2; ++f)
#pragma unroll
                for (int i = 0; i < 4; ++i) {
                    int row = ah * 4 + i, col = w * 32 + f * 16 + arow;
                    hur[row][col] = f2bf(tanhf(a[f][i]));
                }
        }
        __syncthreads();

        // ---- G_o2: y_ode = y + (h_o @ Wo2 + bo2)*dt -> yof fp32, cat[:,0:256] bf16 ----
        {
            f4v a[2];
#pragma unroll
            for (int f = 0; f < 2; ++f) {
                float b = bo2[w * 32 + f * 16 + arow];
                a[f] = (f4v){b, b, b, b};
            }
            mmloop<256, 2>(&hur[0][0], HURP, W + OFF_WO2, 256, w * 32, a, arow, ah);
#pragma unroll
            for (int f = 0; f < 2; ++f)
#pragma unroll
                for (int i = 0; i < 4; ++i) {
                    int row = ah * 4 + i, col = w * 32 + f * 16 + arow;
                    float yo = yf[row][col] + a[f][i] * dtv;
                    yof[row][col] = yo;
                    cat[row][col] = f2bf(yo);
                }
        }
        __syncthreads();

        // ---- G_ur1: [hu|hr] = tanh(yc @ [Wu1|Wr1] + [bu1|br1]) -> hur[:,0:1024] ----
        {
            f4v a[8];
#pragma unroll
            for (int f = 0; f < 8; ++f) {
                int j = w * 128 + f * 16 + arow;
                float b = (j < 512) ? bu1[j] : br1[j - 512];
                a[f] = (f4v){b, b, b, b};
            }
            mmloop<640, 8>(&cat[0][0], CATP, W + OFF_WUR1, 640, w * 128, a, arow, ah);
#pragma unroll
            for (int f = 0; f < 8; ++f)
#pragma unroll
                for (int i = 0; i < 4; ++i) {
                    int row = ah * 4 + i, col = w * 128 + f * 16 + arow;
                    hur[row][col] = f2bf(tanhf(a[f][i]));
                }
        }
        __syncthreads();

        // ---- G_ur2: u = sig(hu@Wu2+bu2) (waves 0-3), r = sig(hr@Wr2+br2) (waves 4-7) ----
        {
            f4v a[4];
#pragma unroll
            for (int f = 0; f < 4; ++f) {
                int j = w * 64 + f * 16 + arow;
                float b = (j < 256) ? bu2[j] : br2[j - 256];
                a[f] = (f4v){b, b, b, b};
            }
            const int aoff = (w < 4) ? 0 : 512;
            mmloop<512, 4>(&hur[0][0] + aoff, HURP, W + OFF_WUR2, 512, w * 64, a, arow, ah);
#pragma unroll
            for (int f = 0; f < 4; ++f)
#pragma unroll
                for (int i = 0; i < 4; ++i) {
                    int row = ah * 4 + i, j = w * 64 + f * 16 + arow;
                    float sg = 1.f / (1.f + expf(-a[f][i]));
                    if (j < 256) uf[row][j] = sg;
                    else         rf[row][j - 256] = sg;
                }
        }
        __syncthreads();

        // ---- c2 = [y_ode*r | s*r | x] -> overwrite cat[:,0:512] ----
        for (int i = tid; i < ROWS * 512; i += NTHR) {
            int r = i >> 9, c = i & 511;
            float base = (c < 256) ? yof[r][c] : sf[r][c & 255];
            cat[r][c] = f2bf(base * rf[r][c & 255]);
        }
        __syncthreads();

        // ---- G_n1: hn = tanh(c2 @ Wn1 + bn1) -> hur[:,0:512] ----
        {
            f4v a[4];
#pragma unroll
            for (int f = 0; f < 4; ++f) {
                float b = bn1[w * 64 + f * 16 + arow];
                a[f] = (f4v){b, b, b, b};
            }
            mmloop<640, 4>(&cat[0][0], CATP, W + OFF_WN1, 640, w * 64, a, arow, ah);
#pragma unroll
            for (int f = 0; f < 4; ++f)
#pragma unroll
                for (int i = 0; i < 4; ++i) {
                    int row = ah * 4 + i, col = w * 64 + f * 16 + arow;
                    hur[row][col] = f2bf(tanhf(a[f][i]));
                }
        }
        __syncthreads();

        // ---- G_n2: ns = hn @ Wn2 + bn2 ; fused state update ----
        {
            f4v a[4];
#pragma unroll
            for (int f = 0; f < 4; ++f) {
                float b = bn2[w * 64 + f * 16 + arow];
                a[f] = (f4v){b, b, b, b};
            }
            mmloop<512, 4>(&hur[0][0], HURP, W + OFF_WN2, 512, w * 64, a, arow, ah);
#pragma unroll
            for (int f = 0; f < 4; ++f)
#pragma unroll
                for (int i = 0; i < 4; ++i) {
                    int row = ah * 4 + i, j = w * 64 + f * 16 + arow;
                    float val = a[f][i];
                    bool m = msum[row] > 0.f;
                    if (j < 256) {               // new_state -> y
                        float u  = uf[row][j];
                        float yo = yof[row][j];
                        float ny = (1.f - u) * val + u * yo;
                        float yn = m ? ny : yo;
                        yf[row][j] = yn;
                        cat[row][j] = f2bf(yn);
                    } else {                     // new_std -> s
                        int c = j - 256;
                        float u  = uf[row][c];
                        float so = sf[row][c];
                        float nstd = (1.f - u) * fabsf(val) + u * so;
                        float sn = m ? nstd : so;
                        sn = fabsf(sn);
                        sf[row][c] = sn;
                        cat[row][256 + c] = f2bf(sn);
                    }
                }
        }
        __syncthreads();
    }

    // ---- final head (fp32, run once): z = tanh([y|s]@Wt1+bt1)@Wt2+bt2 ----
    for (int it = tid; it < ROWS * 100; it += NTHR) {
        int r = it / 100, j = it - r * 100;
        float acc = bt1[j];
        for (int k = 0; k < 256; ++k) acc += yf[r][k] * Wt1[k * 100 + j];
        for (int k = 0; k < 256; ++k) acc += sf[r][k] * Wt1[(256 + k) * 100 + j];
        z1s[r][j] = tanhf(acc);
    }
    __syncthreads();
    for (int it = tid; it < ROWS * 512; it += NTHR) {
        int r = it >> 9, j = it & 511;
        float acc = bt2[j];
        for (int k = 0; k < 100; ++k) acc += z1s[r][k] * Wt2[k * 512 + j];
        int bg = r0 + r;
        if (j < 256) {
            out[(size_t)bg * 256 + j] = acc;
        } else {
            float v = fabsf(acc);
            if (v < 1e-20f) v = 1e-20f;
            out[(size_t)B_TOT * 256 + (size_t)bg * 256 + (j - 256)] = v;
        }
    }
}

extern "C" void kernel_launch(void* const* d_in, const int* in_sizes, int n_in,
                              void* d_out, int out_size, void* d_ws, size_t ws_size,
                              hipStream_t stream) {
    const float* data = (const float*)d_in[0];
    const float* ts   = (const float*)d_in[1];
    const float* Wu1  = (const float*)d_in[2];
    const float* bu1  = (const float*)d_in[3];
    const float* Wu2  = (const float*)d_in[4];
    const float* bu2  = (const float*)d_in[5];
    const float* Wr1  = (const float*)d_in[6];
    const float* br1  = (const float*)d_in[7];
    const float* Wr2  = (const float*)d_in[8];
    const float* br2  = (const float*)d_in[9];
    const float* Wn1  = (const float*)d_in[10];
    const float* bn1  = (const float*)d_in[11];
    const float* Wn2  = (const float*)d_in[12];
    const float* bn2  = (const float*)d_in[13];
    const float* Wo1  = (const float*)d_in[14];
    const float* bo1  = (const float*)d_in[15];
    const float* Wo2  = (const float*)d_in[16];
    const float* bo2  = (const float*)d_in[17];
    const float* Wt1  = (const float*)d_in[18];
    const float* bt1  = (const float*)d_in[19];
    const float* Wt2  = (const float*)d_in[20];
    const float* bt2  = (const float*)d_in[21];
    unsigned short* ws = (unsigned short*)d_ws;
    float* out = (float*)d_out;

    prep_weights<<<(WS_ELEMS + 255) / 256, 256, 0, stream>>>(
        Wu1, Wr1, Wu2, Wr2, Wn1, Wn2, Wo1, Wo2, ws);
    odernn_main<<<NBLK, NTHR, 0, stream>>>(
        data, ts, bu1, bu2, br1, br2, bn1, bn2, bo1, bo2,
        Wt1, bt1, Wt2, bt2, ws, out);
}